// Round 10
// baseline (313.901 us; speedup 1.0000x reference)
//
#include <hip/hip_runtime.h>
#include <hip/hip_bf16.h>

#define NL 3
#define HD 64
#define TCAP 2048
#define NB 8
#define FLG (1<<30)
#define MSK (FLG-1)

typedef unsigned char u8;

__device__ __forceinline__ float sigf(float x){ return 1.f/(1.f+__expf(-x)); }

__device__ __forceinline__ float wsum(float v){
  #pragma unroll
  for (int off=32; off; off>>=1) v += __shfl_xor(v, off, 64);
  return v;
}

__device__ __forceinline__ float bcastf(float v, int l){
  return __int_as_float(__builtin_amdgcn_readlane(__float_as_int(v), l));
}

__device__ __forceinline__ float ldin(const void* p, size_t i, int bf){
  return bf ? __bfloat162float(((const __hip_bfloat16*)p)[i]) : ((const float*)p)[i];
}

// -------- runtime dtype probe --------
__global__ void k_dtype(const unsigned short* __restrict__ probe, int* __restrict__ flag){
  int lane = threadIdx.x & 63;
  unsigned short h = probe[lane];
  int e = (h >> 7) & 0xFF;
  int sane = ((h & 0x7FFF) == 0) || (e >= 96 && e <= 132);
  unsigned long long m = __ballot(sane != 0);
  if (lane == 0) flag[0] = (__popcll(m) >= 56) ? 1 : 0;
}

// -------- convert weights to f32 scratch (input-major layouts) --------
__global__ void k_prep(
    const void* __restrict__ W_h, const void* __restrict__ Ws,
    const void* __restrict__ Wih, const void* __restrict__ Whh,
    const void* __restrict__ bih, const void* __restrict__ bhh,
    const void* __restrict__ wal, const void* __restrict__ bal,
    const void* __restrict__ Wf,  const void* __restrict__ rel,
    float* __restrict__ WhF, float* __restrict__ WsF,
    float* __restrict__ WiT, float* __restrict__ WhT,
    float* __restrict__ biF, float* __restrict__ bhF,
    float* __restrict__ waF, float* __restrict__ baF,
    float* __restrict__ WfF, float* __restrict__ REL,
    const int* __restrict__ flag, int NR)
{
  int bf = flag[0];
  int j = blockIdx.x*256 + threadIdx.x;
  const int sWT = NL*HD*HD, sWI = NL*192*HD, sB = NL*192;
  if (j < sWT){ WhF[j]=ldin(W_h,j,bf); return; } j-=sWT;
  if (j < sWT){ WsF[j]=ldin(Ws ,j,bf); return; } j-=sWT;
  if (j < sWI){ int l=j/(192*HD), q=j%(192*HD), h=q/192, a=q%192;
                WiT[j]=ldin(Wih,(size_t)l*192*HD + (size_t)a*HD + h,bf); return; } j-=sWI;
  if (j < sWI){ int l=j/(192*HD), q=j%(192*HD), h=q/192, a=q%192;
                WhT[j]=ldin(Whh,(size_t)l*192*HD + (size_t)a*HD + h,bf); return; } j-=sWI;
  if (j < sB){ biF[j]=ldin(bih,j,bf); return; } j-=sB;
  if (j < sB){ bhF[j]=ldin(bhh,j,bf); return; } j-=sB;
  if (j < NL*HD){ waF[j]=ldin(wal,j,bf); return; } j-=NL*HD;
  if (j < NL){ baF[j]=ldin(bal,j,bf); return; } j-=NL;
  if (j < HD){ WfF[j]=ldin(Wf,j,bf); return; } j-=HD;
  if (j < NL*NR*HD){ REL[j]=ldin(rel,j,bf); return; }
}

// -------- per-(layer,rel) hr@Wr and per-(layer,batch) h_qr@Wqr+bqr tables --------
__global__ void k_tables(
    const void* __restrict__ rel, const void* __restrict__ Wr,
    const void* __restrict__ Wqr, const void* __restrict__ bqr,
    const int* __restrict__ q_rel,
    float* __restrict__ R2, float* __restrict__ QR,
    const int* __restrict__ flag, int NR, int B)
{
  int bf = flag[0];
  int lane = threadIdx.x & 63;
  int bid = blockIdx.x;
  if (bid < NL*NR){
    int l = bid/NR, r = bid%NR;
    float x = ldin(rel,(size_t)(l*NR+r)*HD + lane,bf);
    float acc = 0.f;
    #pragma unroll
    for (int h=0; h<HD; ++h)
      acc = fmaf(bcastf(x, h), ldin(Wr,(size_t)(l*HD+h)*HD + lane,bf), acc);
    R2[(size_t)bid*HD + lane] = acc;
  } else {
    int b2 = bid - NL*NR;
    int l = b2/B, b = b2%B;
    int r = q_rel[b];
    float x = ldin(rel,(size_t)(l*NR+r)*HD + lane,bf);
    float acc = ldin(bqr,(size_t)l*HD + lane,bf);
    #pragma unroll
    for (int h=0; h<HD; ++h)
      acc = fmaf(bcastf(x, h), ldin(Wqr,(size_t)(l*HD+h)*HD + lane,bf), acc);
    QR[(size_t)b2*HD + lane] = acc;
  }
}

// -------- CSR build over sub: histogram, 2-level exclusive scan, scatter --------
__global__ void k_hist(const int* __restrict__ sub, int* __restrict__ cnt, int E){
  int e = blockIdx.x*256 + threadIdx.x;
  if (e < E) atomicAdd(&cnt[sub[e]], 1);
}

__global__ void k_scanA(const int* __restrict__ cnt, int* __restrict__ rowptr,
                        int* __restrict__ bsum, int N){
  __shared__ int sh[256];
  int i = blockIdx.x*256 + threadIdx.x;
  int v = (i<N) ? cnt[i] : 0;
  sh[threadIdx.x] = v;
  __syncthreads();
  int inc = v;
  for (int off=1; off<256; off<<=1){
    int t = (threadIdx.x>=off) ? sh[threadIdx.x-off] : 0;
    __syncthreads();
    inc += t; sh[threadIdx.x] = inc;
    __syncthreads();
  }
  if (i<N) rowptr[i] = inc - v;                 // exclusive within block
  if (threadIdx.x==255) bsum[blockIdx.x] = inc; // block total
}

__global__ void k_scanB(int* __restrict__ bsum, int nblk){
  __shared__ int sh[1024];
  int t = threadIdx.x;
  int v = (t<nblk) ? bsum[t] : 0;
  sh[t] = v;
  __syncthreads();
  int inc = v;
  for (int off=1; off<1024; off<<=1){
    int x = (t>=off) ? sh[t-off] : 0;
    __syncthreads();
    inc += x; sh[t] = inc;
    __syncthreads();
  }
  if (t<nblk) bsum[t] = inc - v;                // exclusive block offsets
}

__global__ void k_scanC(int* __restrict__ rowptr, const int* __restrict__ bsum,
                        const int* __restrict__ cnt, int N){
  int i = blockIdx.x*256 + threadIdx.x;
  if (i<N){
    int v = rowptr[i] + bsum[blockIdx.x];
    rowptr[i] = v;
    if (i==N-1) rowptr[N] = v + cnt[i];
  }
}

__global__ void k_scatter(const int* __restrict__ sub, const int* __restrict__ rel_i,
                          const int* __restrict__ obj, const int* __restrict__ eb,
                          const int* __restrict__ rowptr, int* __restrict__ cnt2,
                          int* __restrict__ objE, int* __restrict__ relE,
                          int* __restrict__ ebE, int E){
  int e = blockIdx.x*256 + threadIdx.x;
  if (e >= E) return;
  int s = sub[e];
  int p = rowptr[s] + atomicAdd(&cnt2[s], 1);
  objE[p] = obj[e]; relE[p] = rel_i[e]; ebE[p] = eb[e];
}

// -------- seed query nodes (one block per b; last-writer-wins dedupe) --------
__global__ void k_init(
    const int* __restrict__ qsub, const int* __restrict__ q_rel,
    const void* __restrict__ qre,
    float* __restrict__ hid, int* __restrict__ stamp,
    int* __restrict__ liveL, int* __restrict__ liveCnt,
    const int* __restrict__ flag, int B)
{
  int bf = flag[0];
  int lane = threadIdx.x & 63;
  int b = blockIdx.x;
  int n = qsub[b];
  for (int b2=b+1; b2<B; ++b2) if (qsub[b2]==n) return;  // last dup wins
  int r = q_rel[b];
  hid[(size_t)n*HD + lane] = ldin(qre,(size_t)r*HD + lane,bf);
  if (lane==0){
    stamp[n] = 1;                       // "live entering layer 0" epoch
    int i = atomicAdd(liveCnt, 1);
    liveL[i] = n;
  }
}

// -------- edge phase over LIVE SUBS via CSR (no full-E scan) --------
__global__ void __launch_bounds__(256) k_edge2(
    const int* __restrict__ liveL, const int* __restrict__ liveCnt,
    const int* __restrict__ rowptr, const int* __restrict__ objE,
    const int* __restrict__ relE, const int* __restrict__ ebE,
    const float* __restrict__ hid, const float* __restrict__ WsFl,
    const float* __restrict__ R2l, const float* __restrict__ QRl,
    const float* __restrict__ RELl, const float* __restrict__ waFl,
    const float* __restrict__ baFl, float* __restrict__ agg,
    int* __restrict__ stamp, int* __restrict__ tlist, int* __restrict__ tcnt,
    int ep, int N)
{
  __shared__ int s_cnt;
  __shared__ int s_base;
  __shared__ int s_buf[TCAP];
  if (threadIdx.x == 0) s_cnt = 0;
  __syncthreads();

  int nlive = liveCnt[0]; if (nlive > N) nlive = N;
  int lane = threadIdx.x & 63;
  int wid = (blockIdx.x*256 + threadIdx.x) >> 6;
  int nw = gridDim.x*4;
  float wa = waFl[lane];
  float ba = baFl[0];

  for (int i = wid; i < nlive; i += nw){
    int s = liveL[i];
    float hs = hid[(size_t)s*HD + lane];
    // hsw = hs @ Ws[l], once per sub (weights L2-hot)
    float hsw = 0.f;
    #pragma unroll 8
    for (int h=0; h<HD; ++h)
      hsw = fmaf(bcastf(hs,h), WsFl[h*HD + lane], hsw);
    int r0 = rowptr[s], r1 = rowptr[s+1];
    for (int j = r0; j < r1; ++j){
      int o = objE[j], r = relE[j], b = ebE[j];   // contiguous, L1-hot
      float pre = hsw + R2l[(size_t)r*HD + lane] + QRl[(size_t)b*HD + lane];
      pre = fmaxf(pre, 0.f);
      float alpha = sigf(wsum(pre*wa) + ba);
      unsafeAtomicAdd(&agg[(size_t)o*HD + lane], alpha * hs * RELl[(size_t)r*HD + lane]);
      if (lane==0){
        int old = atomicExch(&stamp[o], ep);
        if (old != ep){
          int v = o | ((old == ep-1) ? FLG : 0);  // flag: was live entering this layer
          int li = atomicAdd(&s_cnt, 1);
          if (li < TCAP) s_buf[li] = v;
          else { int gi = atomicAdd(tcnt, 1); tlist[gi] = v; }
        }
      }
    }
  }

  __syncthreads();
  int cnt = s_cnt; if (cnt > TCAP) cnt = TCAP;
  if (threadIdx.x == 0 && cnt > 0) s_base = atomicAdd(tcnt, cnt);
  __syncthreads();
  if (cnt > 0){
    int b0 = s_base;
    for (int i = threadIdx.x; i < cnt; i += 256) tlist[b0 + i] = s_buf[i];
  }
}

// -------- node phase: NB nodes/wave; Whh matvec only for prev-live; builds live list --------
__global__ void __launch_bounds__(256) k_node(
    const int* __restrict__ tlist, const int* __restrict__ tcnt,
    float* __restrict__ agg, float* __restrict__ hid,
    const float* __restrict__ WhFl,  // [H][H]
    const float* __restrict__ WiTl,  // [H][3H]
    const float* __restrict__ WhTl,  // [H][3H]
    const float* __restrict__ biFl, const float* __restrict__ bhFl,
    const float* __restrict__ WfF,
    int* __restrict__ stamp, int* __restrict__ liveL, int* __restrict__ liveCnt,
    float* __restrict__ out, int N, int isFirst, int isLast, int ep)
{
  __shared__ int s_cnt;
  __shared__ int s_base;
  __shared__ int s_buf[TCAP];
  if (threadIdx.x == 0) s_cnt = 0;
  __syncthreads();

  int cntv = tcnt[0]; if (cntv > N) cntv = N;
  int lane = threadIdx.x & 63;
  int wid = (blockIdx.x*256 + threadIdx.x) >> 6;
  int nw = gridDim.x*4;
  float bi0=biFl[lane], bi1=biFl[HD+lane], bi2=biFl[2*HD+lane];
  float bh0=bhFl[lane], bh1=bhFl[HD+lane], bh2=bhFl[2*HD+lane];
  float wfv = isLast ? WfF[lane] : 0.f;

  for (int i0 = wid*NB; i0 < cntv; i0 += nw*NB){
    int nd[NB]; bool val[NB]; bool wp[NB]; float av[NB];
    #pragma unroll
    for (int j=0;j<NB;++j){
      val[j] = (i0+j) < cntv;
      int v  = tlist[val[j] ? (i0+j) : i0];
      nd[j]  = v & MSK;
      wp[j]  = (!isFirst) && val[j] && ((v & FLG) != 0);
      av[j]  = val[j] ? agg[(size_t)nd[j]*HD + lane] : 0.f;
    }
    if (!isLast){
      #pragma unroll
      for (int j=0;j<NB;++j) if (val[j]) agg[(size_t)nd[j]*HD + lane] = 0.f;
    }

    // hm = relu(av @ W_h)
    float hm[NB];
    #pragma unroll
    for (int j=0;j<NB;++j) hm[j] = 0.f;
    #pragma unroll 8
    for (int h=0; h<HD; ++h){
      float w = WhFl[h*HD + lane];
      #pragma unroll
      for (int j=0;j<NB;++j) hm[j] = fmaf(bcastf(av[j],h), w, hm[j]);
    }
    float mask[NB]; float h0v[NB];
    #pragma unroll
    for (int j=0;j<NB;++j){
      hm[j] = fmaxf(hm[j], 0.f);
      mask[j] = (__ballot(hm[j] != 0.f) != 0ull) ? 1.f : 0.f;
      h0v[j] = wp[j] ? hid[(size_t)nd[j]*HD + lane] : 0.f;   // wp wave-uniform
    }

    float gi0[NB], gi1[NB], gi2[NB], gh0[NB], gh1[NB], gh2[NB];
    #pragma unroll
    for (int j=0;j<NB;++j){ gi0[j]=bi0; gi1[j]=bi1; gi2[j]=bi2; gh0[j]=bh0; gh1[j]=bh1; gh2[j]=bh2; }
    #pragma unroll 4
    for (int h=0; h<HD; ++h){
      const float* __restrict__ wr = WiTl + (size_t)h*192;
      float w0 = wr[lane], w1 = wr[64+lane], w2 = wr[128+lane];
      #pragma unroll
      for (int j=0;j<NB;++j){
        float x = bcastf(hm[j],h);
        gi0[j] = fmaf(x, w0, gi0[j]);
        gi1[j] = fmaf(x, w1, gi1[j]);
        gi2[j] = fmaf(x, w2, gi2[j]);
      }
    }
    // Whh matvec only for nodes that were live (wave-uniform per j)
    #pragma unroll
    for (int j=0;j<NB;++j){
      if (wp[j]){
        #pragma unroll 4
        for (int h=0; h<HD; ++h){
          const float* __restrict__ wr = WhTl + (size_t)h*192;
          float y = bcastf(h0v[j],h);
          gh0[j] = fmaf(y, wr[lane],     gh0[j]);
          gh1[j] = fmaf(y, wr[64+lane],  gh1[j]);
          gh2[j] = fmaf(y, wr[128+lane], gh2[j]);
        }
      }
    }

    float hn[NB];
    #pragma unroll
    for (int j=0;j<NB;++j){
      float r = sigf(gi0[j]+gh0[j]);
      float z = sigf(gi1[j]+gh1[j]);
      float nn = tanhf(gi2[j] + r*gh2[j]);
      hn[j] = ((1.f - z)*nn + z*h0v[j])*mask[j];
    }

    if (isLast){
      #pragma unroll
      for (int j=0;j<NB;++j){
        float sc = wsum(hn[j] * wfv);
        if (lane==0 && val[j]) out[nd[j]] = sc;
      }
      continue;
    }
    #pragma unroll
    for (int j=0;j<NB;++j){
      unsigned long long lv = __ballot(hn[j] != 0.f);
      if (val[j]){
        hid[(size_t)nd[j]*HD + lane] = hn[j];
        if (lane==0){
          if (lv){
            int li = atomicAdd(&s_cnt, 1);
            if (li < TCAP) s_buf[li] = nd[j];
            else { int gi = atomicAdd(liveCnt, 1); liveL[gi] = nd[j]; }
          } else {
            stamp[nd[j]] = 0;   // died: demote so next layer's wasPrev is false
          }
        }
      }
    }
  }

  __syncthreads();
  int c = s_cnt; if (c > TCAP) c = TCAP;
  if (threadIdx.x == 0 && c > 0) s_base = atomicAdd(liveCnt, c);
  __syncthreads();
  if (c > 0){
    int b0 = s_base;
    for (int i = threadIdx.x; i < c; i += 256) liveL[b0 + i] = s_buf[i];
  }
}

extern "C" void kernel_launch(void* const* d_in, const int* in_sizes, int n_in,
                              void* d_out, int out_size, void* d_ws, size_t ws_size,
                              hipStream_t stream)
{
  const int* sub   = (const int*)d_in[0];
  const int* rel_i = (const int*)d_in[1];
  const int* obj   = (const int*)d_in[2];
  const int* eb    = (const int*)d_in[3];
  const int* q_rel = (const int*)d_in[4];
  const int* qsub  = (const int*)d_in[5];
  const void* rela = d_in[6];
  const void* qre  = d_in[7];
  const void* Wsp  = d_in[8];
  const void* Wr   = d_in[9];
  const void* Wqr  = d_in[10];
  const void* bqr  = d_in[11];
  const void* wal  = d_in[12];
  const void* bal  = d_in[13];
  const void* W_h  = d_in[14];
  const void* Wih  = d_in[15];
  const void* Whh  = d_in[16];
  const void* bih  = d_in[17];
  const void* bhh  = d_in[18];
  const void* Wf   = d_in[19];

  int E  = in_sizes[0];
  int B  = in_sizes[4];
  int NR = in_sizes[6]/(NL*HD);
  int N  = out_size;
  int NBLK = (N + 255) / 256;

  float* ws = (float*)d_ws;
  size_t o = 0;
  float* agg  = ws + o; o += (size_t)N*HD;     // memset 0 each call
  float* hid  = ws + o; o += (size_t)N*HD;     // reads guarded by stamp/flags
  float* R2   = ws + o; o += (size_t)NL*NR*HD;
  float* QR   = ws + o; o += (size_t)NL*B*HD;
  float* REL  = ws + o; o += (size_t)NL*NR*HD;
  float* WhF  = ws + o; o += NL*HD*HD;
  float* WsF  = ws + o; o += NL*HD*HD;
  float* WiT  = ws + o; o += NL*192*HD;
  float* WhT  = ws + o; o += NL*192*HD;
  float* biF  = ws + o; o += NL*192;
  float* bhF  = ws + o; o += NL*192;
  float* waF  = ws + o; o += NL*HD;
  float* baF  = ws + o; o += NL;
  float* WfF  = ws + o; o += HD;
  int*   rowptr = (int*)(ws + o); o += (size_t)N + 1;
  int*   bsum   = (int*)(ws + o); o += 1024;
  int*   liveL  = (int*)(ws + o); o += N;
  int*   touchL = (int*)(ws + o); o += N;
  int*   objE   = (int*)(ws + o); o += E;
  int*   relE   = (int*)(ws + o); o += E;
  int*   ebE    = (int*)(ws + o); o += E;
  int*   cntH   = (int*)(ws + o); o += N;      // ┐ contiguous zero region:
  int*   cnt2   = (int*)(ws + o); o += N;      // │ cntH + cnt2 + stamp + cnts
  int*   stamp  = (int*)(ws + o); o += N;      // │
  int*   cnts   = (int*)(ws + o); o += 16;     // ┘

  // cnts: [0..2]=touched counts, [4..6]=live-in counts (L0 from init), [7]=sink, [8]=dtype
  hipMemsetAsync(agg,  0, (size_t)N*HD*sizeof(float), stream);
  hipMemsetAsync(cntH, 0, ((size_t)3*N + 16)*sizeof(int), stream);
  hipMemsetAsync(d_out, 0, (size_t)N*sizeof(float), stream);

  k_dtype<<<1, 64, 0, stream>>>((const unsigned short*)rela, cnts+8);

  int prepN = 2*(NL*HD*HD) + 2*(NL*192*HD) + 2*(NL*192) + NL*HD + NL + HD + NL*NR*HD;
  k_prep<<<(prepN+255)/256, 256, 0, stream>>>(W_h, Wsp, Wih, Whh, bih, bhh, wal, bal, Wf, rela,
      WhF, WsF, WiT, WhT, biF, bhF, waF, baF, WfF, REL, cnts+8, NR);
  k_tables<<<NL*NR + NL*B, 64, 0, stream>>>(rela, Wr, Wqr, bqr, q_rel, R2, QR, cnts+8, NR, B);

  // CSR over sub (static across layers/calls)
  k_hist   <<<(E+255)/256, 256, 0, stream>>>(sub, cntH, E);
  k_scanA  <<<NBLK, 256, 0, stream>>>(cntH, rowptr, bsum, N);
  k_scanB  <<<1, 1024, 0, stream>>>(bsum, NBLK);
  k_scanC  <<<NBLK, 256, 0, stream>>>(rowptr, bsum, cntH, N);
  k_scatter<<<(E+255)/256, 256, 0, stream>>>(sub, rel_i, obj, eb, rowptr, cnt2,
                                             objE, relE, ebE, E);

  k_init<<<B, 64, 0, stream>>>(qsub, q_rel, qre, hid, stamp, liveL, cnts+4, cnts+8, B);

  for (int l=0; l<NL; ++l){
    int ep = l + 2;
    k_edge2<<<512, 256, 0, stream>>>(liveL, cnts+4+l, rowptr, objE, relE, ebE,
        hid, WsF + (size_t)l*HD*HD,
        R2 + (size_t)l*NR*HD, QR + (size_t)l*B*HD, REL + (size_t)l*NR*HD,
        waF + l*HD, baF + l, agg, stamp, touchL, cnts+l, ep, N);
    k_node<<<2048, 256, 0, stream>>>(touchL, cnts+l, agg, hid,
        WhF + (size_t)l*HD*HD, WiT + (size_t)l*192*HD, WhT + (size_t)l*192*HD,
        biF + l*192, bhF + l*192, WfF,
        stamp, liveL, (l < NL-1) ? (cnts+4+l+1) : (cnts+7),
        (float*)d_out, N, (l==0)?1:0, (l==NL-1)?1:0, ep);
  }
}

// Round 11
// 188.119 us; speedup vs baseline: 1.6686x; 1.6686x over previous
//
#include <hip/hip_runtime.h>
#include <hip/hip_bf16.h>

#define NL 3
#define HD 64
#define TCAP 2048
#define NB 8

typedef unsigned char u8;

__device__ __forceinline__ float sigf(float x){ return 1.f/(1.f+__expf(-x)); }

__device__ __forceinline__ float wsum(float v){
  #pragma unroll
  for (int off=32; off; off>>=1) v += __shfl_xor(v, off, 64);
  return v;
}

// broadcast lane l's value to all lanes (no LDS)
__device__ __forceinline__ float bcastf(float v, int l){
  return __int_as_float(__builtin_amdgcn_readlane(__float_as_int(v), l));
}

// dtype-flexible load: bf==1 -> bf16, bf==0 -> f32
__device__ __forceinline__ float ldin(const void* p, size_t i, int bf){
  return bf ? __bfloat162float(((const __hip_bfloat16*)p)[i]) : ((const float*)p)[i];
}

// -------- runtime dtype probe --------
__global__ void k_dtype(const unsigned short* __restrict__ probe, int* __restrict__ flag){
  int lane = threadIdx.x & 63;
  unsigned short h = probe[lane];
  int e = (h >> 7) & 0xFF;
  int sane = ((h & 0x7FFF) == 0) || (e >= 96 && e <= 132);
  unsigned long long m = __ballot(sane != 0);
  if (lane == 0) flag[0] = (__popcll(m) >= 56) ? 1 : 0;
}

// -------- convert weights to f32 scratch (input-major layouts) --------
__global__ void k_prep(
    const void* __restrict__ W_h, const void* __restrict__ Ws,
    const void* __restrict__ Wih, const void* __restrict__ Whh,
    const void* __restrict__ bih, const void* __restrict__ bhh,
    const void* __restrict__ wal, const void* __restrict__ bal,
    const void* __restrict__ Wf,  const void* __restrict__ rel,
    float* __restrict__ WhF, float* __restrict__ WsF,
    float* __restrict__ WiT, float* __restrict__ WhT,
    float* __restrict__ biF, float* __restrict__ bhF,
    float* __restrict__ waF, float* __restrict__ baF,
    float* __restrict__ WfF, float* __restrict__ REL,
    const int* __restrict__ flag, int NR)
{
  int bf = flag[0];
  int j = blockIdx.x*256 + threadIdx.x;
  const int sWT = NL*HD*HD, sWI = NL*192*HD, sB = NL*192;
  if (j < sWT){ WhF[j]=ldin(W_h,j,bf); return; } j-=sWT;
  if (j < sWT){ WsF[j]=ldin(Ws ,j,bf); return; } j-=sWT;
  if (j < sWI){ int l=j/(192*HD), q=j%(192*HD), h=q/192, a=q%192;
                WiT[j]=ldin(Wih,(size_t)l*192*HD + (size_t)a*HD + h,bf); return; } j-=sWI;
  if (j < sWI){ int l=j/(192*HD), q=j%(192*HD), h=q/192, a=q%192;
                WhT[j]=ldin(Whh,(size_t)l*192*HD + (size_t)a*HD + h,bf); return; } j-=sWI;
  if (j < sB){ biF[j]=ldin(bih,j,bf); return; } j-=sB;
  if (j < sB){ bhF[j]=ldin(bhh,j,bf); return; } j-=sB;
  if (j < NL*HD){ waF[j]=ldin(wal,j,bf); return; } j-=NL*HD;
  if (j < NL){ baF[j]=ldin(bal,j,bf); return; } j-=NL;
  if (j < HD){ WfF[j]=ldin(Wf,j,bf); return; } j-=HD;
  if (j < NL*NR*HD){ REL[j]=ldin(rel,j,bf); return; }
}

// -------- per-(layer,rel) hr@Wr and per-(layer,batch) h_qr@Wqr+bqr tables --------
__global__ void k_tables(
    const void* __restrict__ rel, const void* __restrict__ Wr,
    const void* __restrict__ Wqr, const void* __restrict__ bqr,
    const int* __restrict__ q_rel,
    float* __restrict__ R2, float* __restrict__ QR,
    const int* __restrict__ flag, int NR, int B)
{
  int bf = flag[0];
  int lane = threadIdx.x & 63;
  int bid = blockIdx.x;
  if (bid < NL*NR){
    int l = bid/NR, r = bid%NR;
    float x = ldin(rel,(size_t)(l*NR+r)*HD + lane,bf);
    float acc = 0.f;
    #pragma unroll
    for (int h=0; h<HD; ++h)
      acc = fmaf(bcastf(x, h), ldin(Wr,(size_t)(l*HD+h)*HD + lane,bf), acc);
    R2[(size_t)bid*HD + lane] = acc;
  } else {
    int b2 = bid - NL*NR;
    int l = b2/B, b = b2%B;
    int r = q_rel[b];
    float x = ldin(rel,(size_t)(l*NR+r)*HD + lane,bf);
    float acc = ldin(bqr,(size_t)l*HD + lane,bf);
    #pragma unroll
    for (int h=0; h<HD; ++h)
      acc = fmaf(bcastf(x, h), ldin(Wqr,(size_t)(l*HD+h)*HD + lane,bf), acc);
    QR[(size_t)b2*HD + lane] = acc;
  }
}

// -------- seed query nodes IN PARALLEL (one block per b; last-writer-wins dedupe) --------
__global__ void k_init(
    const int* __restrict__ qsub, const int* __restrict__ q_rel,
    const void* __restrict__ qre, const float* __restrict__ WsF0,
    float* __restrict__ hid, float* __restrict__ HS2, u8* __restrict__ liveB,
    int* __restrict__ stamp, int* __restrict__ plist, int* __restrict__ pcnt,
    const int* __restrict__ flag, int B)
{
  int bf = flag[0];
  int lane = threadIdx.x & 63;
  int b = blockIdx.x;
  int n = qsub[b];
  for (int b2 = b+1; b2 < B; ++b2) if (qsub[b2] == n) return;  // last dup wins
  int r = q_rel[b];
  float v = ldin(qre,(size_t)r*HD + lane,bf);
  hid[(size_t)n*HD + lane] = v;
  float acc = 0.f;
  #pragma unroll 8
  for (int h=0; h<HD; ++h)
    acc = fmaf(bcastf(v,h), WsF0[h*HD + lane], acc);
  HS2[(size_t)n*HD + lane] = acc;
  if (lane==0){
    liveB[n] = 1;
    stamp[n] = 1;
    int idx = atomicAdd(pcnt, 1);
    plist[idx] = n;
  }
}

// -------- fused edge phase: 4 edges/lane scan (256/window), byte liveB;
//          touched-node appends buffered in LDS, one global atomic per block --------
__global__ void __launch_bounds__(256) k_edge(
    const int* __restrict__ sub, const int* __restrict__ rel_i,
    const int* __restrict__ obj, const int* __restrict__ eb,
    const u8* __restrict__ liveB,
    const float* __restrict__ hid, const float* __restrict__ HS2,
    const float* __restrict__ R2l, const float* __restrict__ QRl,
    const float* __restrict__ RELl, const float* __restrict__ waFl,
    const float* __restrict__ baFl, float* __restrict__ agg,
    int* __restrict__ stamp, int* __restrict__ tlist, int* __restrict__ tcnt,
    int ep, int E)
{
  __shared__ int s_cnt;
  __shared__ int s_base;
  __shared__ int s_buf[TCAP];
  if (threadIdx.x == 0) s_cnt = 0;
  __syncthreads();

  int lane = threadIdx.x & 63;
  int wid = (blockIdx.x*256 + threadIdx.x) >> 6;
  int nw = gridDim.x*4;
  float wa = waFl[lane];
  float ba = baFl[0];

  for (long long base = (long long)wid*256; base < E; base += (long long)nw*256){
    unsigned long long m[4];
    if (base + 256 <= E){
      int4 s4 = *reinterpret_cast<const int4*>(&sub[base + 4*(long long)lane]);
      bool l0 = liveB[s4.x] != 0;
      bool l1 = liveB[s4.y] != 0;
      bool l2 = liveB[s4.z] != 0;
      bool l3 = liveB[s4.w] != 0;
      m[0] = __ballot(l0); m[1] = __ballot(l1);
      m[2] = __ballot(l2); m[3] = __ballot(l3);
    } else {
      #pragma unroll
      for (int j=0;j<4;++j){
        long long e = base + 4*(long long)lane + j;
        bool lv = (e < E) && (liveB[sub[e]] != 0);
        m[j] = __ballot(lv);
      }
    }
    #pragma unroll
    for (int j=0;j<4;++j){
      unsigned long long mask = m[j];
      while (mask){
        int bit = (int)__ffsll(mask) - 1;
        mask &= mask - 1;
        long long ee = base + 4*(long long)bit + j;
        int ss = sub[ee], r = rel_i[ee], o = obj[ee], b = eb[ee];  // wave-uniform
        float hs  = hid[(size_t)ss*HD + lane];
        float pre = HS2[(size_t)ss*HD + lane] + R2l[(size_t)r*HD + lane] + QRl[(size_t)b*HD + lane];
        pre = fmaxf(pre, 0.f);
        float d = wsum(pre*wa) + ba;
        float alpha = sigf(d);
        float msg = alpha * hs * RELl[(size_t)r*HD + lane];
        unsafeAtomicAdd(&agg[(size_t)o*HD + lane], msg);
        if (lane==0){
          int old = atomicExch(&stamp[o], ep);
          if (old != ep){
            int li = atomicAdd(&s_cnt, 1);
            if (li < TCAP) s_buf[li] = o;
            else { int gi = atomicAdd(tcnt, 1); tlist[gi] = o; }
          }
        }
      }
    }
  }

  __syncthreads();
  int cnt = s_cnt; if (cnt > TCAP) cnt = TCAP;
  if (threadIdx.x == 0 && cnt > 0) s_base = atomicAdd(tcnt, cnt);
  __syncthreads();
  if (cnt > 0){
    int b0 = s_base;
    for (int i = threadIdx.x; i < cnt; i += 256) tlist[b0 + i] = s_buf[i];
  }
}

// -------- node phase: NB=8 nodes/wave; Whh matvec skipped unless prev-live --------
__global__ void __launch_bounds__(256) k_node(
    const int* __restrict__ tlist, const int* __restrict__ tcnt,
    float* __restrict__ agg, float* __restrict__ hid, float* __restrict__ HS2,
    u8* __restrict__ liveB,
    const float* __restrict__ WhFl,  // [H][H]
    const float* __restrict__ WiTl,  // [H][3H]
    const float* __restrict__ WhTl,  // [H][3H]
    const float* __restrict__ biFl, const float* __restrict__ bhFl,
    const float* __restrict__ WsFn,  // [H][H] (next layer)
    const float* __restrict__ WfF,
    float* __restrict__ out, int N, int isFirst, int isLast)
{
  int cntv = tcnt[0]; if (cntv > N) cntv = N;
  int lane = threadIdx.x & 63;
  int wid = (blockIdx.x*256 + threadIdx.x) >> 6;
  int nw = gridDim.x*4;
  float bi0=biFl[lane], bi1=biFl[HD+lane], bi2=biFl[2*HD+lane];
  float bh0=bhFl[lane], bh1=bhFl[HD+lane], bh2=bhFl[2*HD+lane];
  float wfv = isLast ? WfF[lane] : 0.f;

  for (int i0 = wid*NB; i0 < cntv; i0 += nw*NB){
    int nd[NB]; bool val[NB]; bool wp[NB]; float av[NB];
    #pragma unroll
    for (int j=0;j<NB;++j){
      val[j] = (i0+j) < cntv;
      nd[j]  = tlist[val[j] ? (i0+j) : i0];
      wp[j]  = (!isFirst) && val[j] && (liveB[nd[j]] != 0);   // read BEFORE overwrite
      av[j]  = val[j] ? agg[(size_t)nd[j]*HD + lane] : 0.f;
    }
    if (!isLast){
      #pragma unroll
      for (int j=0;j<NB;++j) if (val[j]) agg[(size_t)nd[j]*HD + lane] = 0.f;
    }

    // hm = relu(av @ W_h): one weight load feeds NB FMAs
    float hm[NB];
    #pragma unroll
    for (int j=0;j<NB;++j) hm[j] = 0.f;
    #pragma unroll 8
    for (int h=0; h<HD; ++h){
      float w = WhFl[h*HD + lane];
      #pragma unroll
      for (int j=0;j<NB;++j) hm[j] = fmaf(bcastf(av[j],h), w, hm[j]);
    }
    float mask[NB]; float h0v[NB];
    #pragma unroll
    for (int j=0;j<NB;++j){
      hm[j] = fmaxf(hm[j], 0.f);
      mask[j] = (__ballot(hm[j] != 0.f) != 0ull) ? 1.f : 0.f;
      h0v[j] = wp[j] ? hid[(size_t)nd[j]*HD + lane] : 0.f;    // wp wave-uniform
    }

    float gi0[NB], gi1[NB], gi2[NB], gh0[NB], gh1[NB], gh2[NB];
    #pragma unroll
    for (int j=0;j<NB;++j){ gi0[j]=bi0; gi1[j]=bi1; gi2[j]=bi2; gh0[j]=bh0; gh1[j]=bh1; gh2[j]=bh2; }
    #pragma unroll 4
    for (int h=0; h<HD; ++h){
      const float* __restrict__ wr = WiTl + (size_t)h*192;
      float w0 = wr[lane], w1 = wr[64+lane], w2 = wr[128+lane];
      #pragma unroll
      for (int j=0;j<NB;++j){
        float x = bcastf(hm[j],h);
        gi0[j] = fmaf(x, w0, gi0[j]);
        gi1[j] = fmaf(x, w1, gi1[j]);
        gi2[j] = fmaf(x, w2, gi2[j]);
      }
    }
    // Whh matvec only for prev-live nodes (wave-uniform branch per j)
    #pragma unroll
    for (int j=0;j<NB;++j){
      if (wp[j]){
        #pragma unroll 4
        for (int h=0; h<HD; ++h){
          const float* __restrict__ wr = WhTl + (size_t)h*192;
          float y = bcastf(h0v[j],h);
          gh0[j] = fmaf(y, wr[lane],     gh0[j]);
          gh1[j] = fmaf(y, wr[64+lane],  gh1[j]);
          gh2[j] = fmaf(y, wr[128+lane], gh2[j]);
        }
      }
    }

    float hn[NB];
    #pragma unroll
    for (int j=0;j<NB;++j){
      float r = sigf(gi0[j]+gh0[j]);
      float z = sigf(gi1[j]+gh1[j]);
      float nn = tanhf(gi2[j] + r*gh2[j]);
      hn[j] = ((1.f - z)*nn + z*h0v[j])*mask[j];
    }

    if (isLast){
      #pragma unroll
      for (int j=0;j<NB;++j){
        float sc = wsum(hn[j] * wfv);
        if (lane==0 && val[j]) out[nd[j]] = sc;
      }
      continue;
    }
    #pragma unroll
    for (int j=0;j<NB;++j){
      unsigned long long lv = __ballot(hn[j] != 0.f);
      if (val[j]){
        hid[(size_t)nd[j]*HD + lane] = hn[j];
        if (lane==0) liveB[nd[j]] = lv ? (u8)1 : (u8)0;
      }
    }

    // HS2 for next layer: hn @ Ws[l+1]
    float acc[NB];
    #pragma unroll
    for (int j=0;j<NB;++j) acc[j] = 0.f;
    #pragma unroll 8
    for (int h=0; h<HD; ++h){
      float w = WsFn[h*HD + lane];
      #pragma unroll
      for (int j=0;j<NB;++j) acc[j] = fmaf(bcastf(hn[j],h), w, acc[j]);
    }
    #pragma unroll
    for (int j=0;j<NB;++j) if (val[j]) HS2[(size_t)nd[j]*HD + lane] = acc[j];
  }
}

// -------- clear liveness of prev-live nodes that received no messages --------
__global__ void k_died(const int* __restrict__ plist, const int* __restrict__ pcnt,
                       const int* __restrict__ stamp, u8* __restrict__ liveB, int ep, int N)
{
  int cntv = pcnt[0]; if (cntv > N) cntv = N;
  int t = blockIdx.x*256 + threadIdx.x;
  for (int i = t; i < cntv; i += gridDim.x*256){
    int n = plist[i];
    if (stamp[n] != ep) liveB[n] = 0;
  }
}

extern "C" void kernel_launch(void* const* d_in, const int* in_sizes, int n_in,
                              void* d_out, int out_size, void* d_ws, size_t ws_size,
                              hipStream_t stream)
{
  const int* sub   = (const int*)d_in[0];
  const int* rel_i = (const int*)d_in[1];
  const int* obj   = (const int*)d_in[2];
  const int* eb    = (const int*)d_in[3];
  const int* q_rel = (const int*)d_in[4];
  const int* qsub  = (const int*)d_in[5];
  const void* rela = d_in[6];
  const void* qre  = d_in[7];
  const void* Wsp  = d_in[8];
  const void* Wr   = d_in[9];
  const void* Wqr  = d_in[10];
  const void* bqr  = d_in[11];
  const void* wal  = d_in[12];
  const void* bal  = d_in[13];
  const void* W_h  = d_in[14];
  const void* Wih  = d_in[15];
  const void* Whh  = d_in[16];
  const void* bih  = d_in[17];
  const void* bhh  = d_in[18];
  const void* Wf   = d_in[19];

  int E  = in_sizes[0];
  int B  = in_sizes[4];
  int NR = in_sizes[6]/(NL*HD);
  int N  = out_size;

  float* ws = (float*)d_ws;
  size_t o = 0;
  float* agg  = ws + o; o += (size_t)N*HD;     // memset to 0 each call
  float* hid  = ws + o; o += (size_t)N*HD;     // reads guarded by liveB
  float* HS2  = ws + o; o += (size_t)N*HD;     // reads only for live subs
  float* R2   = ws + o; o += (size_t)NL*NR*HD;
  float* QR   = ws + o; o += (size_t)NL*B*HD;
  float* REL  = ws + o; o += (size_t)NL*NR*HD;
  float* WhF  = ws + o; o += NL*HD*HD;
  float* WsF  = ws + o; o += NL*HD*HD;
  float* WiT  = ws + o; o += NL*192*HD;
  float* WhT  = ws + o; o += NL*192*HD;
  float* biF  = ws + o; o += NL*192;
  float* bhF  = ws + o; o += NL*192;
  float* waF  = ws + o; o += NL*HD;
  float* baF  = ws + o; o += NL;
  float* WfF  = ws + o; o += HD;
  int*   listA= (int*)(ws + o); o += N;
  int*   listB= (int*)(ws + o); o += N;
  int*   stamp= (int*)(ws + o); o += N;        // ┐ contiguous memset region:
  int*   cnts = (int*)(ws + o); o += 16;       // │ stamp + cnts + liveB
  u8*    liveB= (u8*)(ws + o);                 // ┘ N bytes

  // cnts: [3]=init live cnt, [4..6]=touched cnts, [8]=dtype flag
  hipMemsetAsync(agg,   0, (size_t)N*HD*sizeof(float), stream);
  hipMemsetAsync(stamp, 0, (size_t)N*sizeof(int) + 16*sizeof(int) + (size_t)N, stream);
  hipMemsetAsync(d_out, 0, (size_t)N*sizeof(float), stream);

  k_dtype<<<1, 64, 0, stream>>>((const unsigned short*)rela, cnts+8);

  int prepN = 2*(NL*HD*HD) + 2*(NL*192*HD) + 2*(NL*192) + NL*HD + NL + HD + NL*NR*HD;
  k_prep<<<(prepN+255)/256, 256, 0, stream>>>(W_h, Wsp, Wih, Whh, bih, bhh, wal, bal, Wf, rela,
      WhF, WsF, WiT, WhT, biF, bhF, waF, baF, WfF, REL, cnts+8, NR);
  k_tables<<<NL*NR + NL*B, 64, 0, stream>>>(rela, Wr, Wqr, bqr, q_rel, R2, QR, cnts+8, NR, B);
  k_init<<<B, 64, 0, stream>>>(qsub, q_rel, qre, WsF, hid, HS2, liveB,
                               stamp, listA, cnts+3, cnts+8, B);

  int* curT = listB;   // touched list this layer
  int* prevL = listA;  // live list before this layer
  for (int l=0; l<NL; ++l){
    int ep = l + 2;
    k_edge<<<1024, 256, 0, stream>>>(sub, rel_i, obj, eb, liveB, hid, HS2,
        R2 + (size_t)l*NR*HD, QR + (size_t)l*B*HD, REL + (size_t)l*NR*HD,
        waF + l*HD, baF + l, agg, stamp, curT, cnts+4+l, ep, E);
    k_node<<<2048, 256, 0, stream>>>(curT, cnts+4+l, agg, hid, HS2, liveB,
        WhF + (size_t)l*HD*HD, WiT + (size_t)l*192*HD, WhT + (size_t)l*192*HD,
        biF + l*192, bhF + l*192,
        (l < NL-1) ? (WsF + (size_t)(l+1)*HD*HD) : WsF,
        WfF, (float*)d_out, N, (l==0)?1:0, (l==NL-1)?1:0);
    if (l < NL-1){
      k_died<<<64, 256, 0, stream>>>(prevL, (l==0) ? (cnts+3) : (cnts+4+l-1),
                                     stamp, liveB, ep, N);
    }
    int* t = prevL; prevL = curT; curT = t;
  }
}